// Round 1
// baseline (844.435 us; speedup 1.0000x reference)
//
#include <hip/hip_runtime.h>

#define N_NODES 30000
#define N_EDGES 480000
#define ETOT    510000   // edges + self loops
#define F_IN    512
#define WIDTH   256
#define NCLS    40

typedef __attribute__((ext_vector_type(8))) short short8;
typedef __attribute__((ext_vector_type(4))) float f32x4;

__device__ __forceinline__ unsigned short f2bf(float f){
  unsigned u = __float_as_uint(f);
  u += 0x7fffu + ((u >> 16) & 1u);   // RTNE
  return (unsigned short)(u >> 16);
}
__device__ __forceinline__ float b2f(unsigned short s){
  return __uint_as_float(((unsigned)s) << 16);
}

// ---------------- cast x (f32 -> bf16), 4 elems/thread ----------------
__global__ void cast4_kernel(const float* __restrict__ in, unsigned short* __restrict__ out, int n4){
  int i = blockIdx.x * blockDim.x + threadIdx.x;
  if (i < n4){
    float4 v = *(const float4*)(in + 4*(size_t)i);
    ushort4 o;
    o.x = f2bf(v.x); o.y = f2bf(v.y); o.z = f2bf(v.z); o.w = f2bf(v.w);
    *(ushort4*)(out + 4*(size_t)i) = o;
  }
}

// ---------------- transpose W [K][Nc] f32 -> Wt [Nc][K] bf16 ----------------
__global__ void transpose_w_kernel(const float* __restrict__ W, unsigned short* __restrict__ Wt,
                                   int K, int Nc){
  int k = blockIdx.x * blockDim.x + threadIdx.x;
  int n = blockIdx.y;
  if (k < K) Wt[(size_t)n * K + k] = f2bf(W[(size_t)k * Nc + n]);
}

// ---------------- CSR build ----------------
__global__ void zero_kernel(int* __restrict__ p, int n){
  int i = blockIdx.x * blockDim.x + threadIdx.x;
  if (i < n) p[i] = 0;
}

__global__ void hist_kernel(const int* __restrict__ ei, int* __restrict__ counts){
  int e = blockIdx.x * blockDim.x + threadIdx.x;
  if (e < ETOT){
    int d = (e < N_EDGES) ? ei[N_EDGES + e] : (e - N_EDGES);
    atomicAdd(&counts[d], 1);
  }
}

__global__ __launch_bounds__(1024) void scan_kernel(const int* __restrict__ counts,
                                                    int* __restrict__ offsets,
                                                    int* __restrict__ cursor, int n){
  __shared__ int wsum[16];
  int tid = threadIdx.x, lane = tid & 63, wid = tid >> 6;
  int running = 0;
  int nchunks = (n + 1023) >> 10;
  for (int ch = 0; ch < nchunks; ++ch){
    int i = (ch << 10) + tid;
    int v = (i < n) ? counts[i] : 0;
    int x = v;
    // wave inclusive scan
    #pragma unroll
    for (int off = 1; off < 64; off <<= 1){
      int t = __shfl_up(x, off, 64);
      if (lane >= off) x += t;
    }
    if (lane == 63) wsum[wid] = x;
    __syncthreads();
    if (wid == 0){
      int s = (lane < 16) ? wsum[lane] : 0;
      #pragma unroll
      for (int off = 1; off < 16; off <<= 1){
        int t = __shfl_up(s, off, 64);
        if (lane >= off) s += t;
      }
      if (lane < 16) wsum[lane] = s;
    }
    __syncthreads();
    int waveprefix = (wid > 0) ? wsum[wid - 1] : 0;
    int excl = x - v + waveprefix + running;
    if (i < n){ offsets[i] = excl; cursor[i] = excl; }
    running += wsum[15];
    __syncthreads();
  }
  if (tid == 0) offsets[n] = running;
}

__global__ void scatter_kernel(const int* __restrict__ ei, int* __restrict__ cursor,
                               int* __restrict__ srcs){
  int e = blockIdx.x * blockDim.x + threadIdx.x;
  if (e < ETOT){
    int s, d;
    if (e < N_EDGES){ s = ei[e]; d = ei[N_EDGES + e]; }
    else { s = e - N_EDGES; d = s; }
    int pos = atomicAdd(&cursor[d], 1);
    srcs[pos] = s;
  }
}

// ---------------- bf16 MFMA GEMM: C[M][256] = A[M][K] @ B[K][256] ----------------
// A is bf16 [M][K]; Bt is bf16 [256][K] (pre-transposed). Single-buffered LDS.
#define BM 64
#define BK 32
#define LDA 40   /* row stride in bf16 elems: 32 + 8 pad (keeps 16B align, spreads banks) */

__global__ __launch_bounds__(256) void gemm_bf16_kernel(const unsigned short* __restrict__ A,
                                                        const unsigned short* __restrict__ Bt,
                                                        float* __restrict__ C,
                                                        int M, int K){
  __shared__ unsigned short Als[BM * LDA];
  __shared__ unsigned short Bls[256 * LDA];
  int tid = threadIdx.x;
  int lane = tid & 63, wid = tid >> 6;
  int l15 = lane & 15, quad = lane >> 4;
  int m0 = blockIdx.x * BM;

  f32x4 acc[16];
  #pragma unroll
  for (int t = 0; t < 16; ++t) acc[t] = (f32x4){0.f, 0.f, 0.f, 0.f};

  for (int k0 = 0; k0 < K; k0 += BK){
    __syncthreads();
    {
      // stage A: 64 rows x 32 cols, 8 bf16 per thread
      int row = tid >> 2, g = tid & 3;
      int grow = m0 + row; if (grow >= M) grow = M - 1;
      uint4 av = *(const uint4*)(A + (size_t)grow * K + k0 + 8 * g);
      *(uint4*)(&Als[row * LDA + 8 * g]) = av;
      // stage B: thread t loads Bt[t][k0..k0+31] (32 bf16 = 4x16B)
      const unsigned short* src = Bt + (size_t)tid * K + k0;
      uint4 b0 = *(const uint4*)(src);
      uint4 b1 = *(const uint4*)(src + 8);
      uint4 b2 = *(const uint4*)(src + 16);
      uint4 b3 = *(const uint4*)(src + 24);
      unsigned short* dst = &Bls[tid * LDA];
      *(uint4*)(dst) = b0;
      *(uint4*)(dst + 8) = b1;
      *(uint4*)(dst + 16) = b2;
      *(uint4*)(dst + 24) = b3;
    }
    __syncthreads();
    short8 af = *(const short8*)(&Als[(16 * wid + l15) * LDA + quad * 8]);
    #pragma unroll
    for (int t = 0; t < 16; ++t){
      short8 bf = *(const short8*)(&Bls[(16 * t + l15) * LDA + quad * 8]);
      acc[t] = __builtin_amdgcn_mfma_f32_16x16x32_bf16(af, bf, acc[t], 0, 0, 0);
    }
  }

  int row0 = m0 + 16 * wid + quad * 4;
  #pragma unroll
  for (int t = 0; t < 16; ++t){
    int col = 16 * t + l15;
    #pragma unroll
    for (int r = 0; r < 4; ++r){
      int grow = row0 + r;
      if (grow < M) C[(size_t)grow * WIDTH + col] = acc[t][r];
    }
  }
}

// ---------------- es/ed + bf16 cast of h ----------------
// wave per node: lane owns channels 4l..4l+3 (head = lane/16)
__global__ __launch_bounds__(256) void esed_kernel(const float* __restrict__ hpre,
                                                   const float* __restrict__ a_s,
                                                   const float* __restrict__ a_d,
                                                   float* __restrict__ es, float* __restrict__ ed,
                                                   unsigned short* __restrict__ hb){
  int n = blockIdx.x * 4 + (threadIdx.x >> 6);
  int lane = threadIdx.x & 63;
  float4 h = *(const float4*)(hpre + (size_t)n * WIDTH + 4 * lane);
  int head = lane >> 4, cl = (lane & 15) * 4;
  float4 as = *(const float4*)(a_s + head * 64 + cl);
  float4 ad = *(const float4*)(a_d + head * 64 + cl);
  float ps = h.x * as.x + h.y * as.y + h.z * as.z + h.w * as.w;
  float pd = h.x * ad.x + h.y * ad.y + h.z * ad.z + h.w * ad.w;
  #pragma unroll
  for (int off = 1; off < 16; off <<= 1){
    ps += __shfl_xor(ps, off, 64);
    pd += __shfl_xor(pd, off, 64);
  }
  if ((lane & 15) == 0){
    es[n * 4 + head] = ps;
    ed[n * 4 + head] = pd;
  }
  ushort4 o;
  o.x = f2bf(h.x); o.y = f2bf(h.y); o.z = f2bf(h.z); o.w = f2bf(h.w);
  *(ushort4*)(hb + (size_t)n * WIDTH + 4 * lane) = o;
}

// ---------------- aggregation: wave per dst node, 2-pass segment softmax ----------------
__global__ __launch_bounds__(256) void agg_kernel(const int* __restrict__ offsets,
                                                  const int* __restrict__ srcs,
                                                  const float* __restrict__ es,
                                                  const float* __restrict__ ed,
                                                  const unsigned short* __restrict__ hb,
                                                  const float* __restrict__ bias,
                                                  unsigned short* __restrict__ hout){
  int n = blockIdx.x * 4 + (threadIdx.x >> 6);
  int lane = threadIdx.x & 63;
  int base = offsets[n];
  int deg = offsets[n + 1] - base;
  float4 edv = *(const float4*)(ed + n * 4);

  // pass 1: per-head max of leaky(es[src]+ed[n])
  float m0 = -1e30f, m1 = -1e30f, m2 = -1e30f, m3 = -1e30f;
  for (int i = lane; i < deg; i += 64){
    int s = srcs[base + i];
    float4 ev = *(const float4*)(es + s * 4);
    float e0 = ev.x + edv.x, e1 = ev.y + edv.y, e2 = ev.z + edv.z, e3 = ev.w + edv.w;
    e0 = e0 > 0.f ? e0 : 0.2f * e0;
    e1 = e1 > 0.f ? e1 : 0.2f * e1;
    e2 = e2 > 0.f ? e2 : 0.2f * e2;
    e3 = e3 > 0.f ? e3 : 0.2f * e3;
    m0 = fmaxf(m0, e0); m1 = fmaxf(m1, e1); m2 = fmaxf(m2, e2); m3 = fmaxf(m3, e3);
  }
  #pragma unroll
  for (int off = 32; off; off >>= 1){
    m0 = fmaxf(m0, __shfl_xor(m0, off, 64));
    m1 = fmaxf(m1, __shfl_xor(m1, off, 64));
    m2 = fmaxf(m2, __shfl_xor(m2, off, 64));
    m3 = fmaxf(m3, __shfl_xor(m3, off, 64));
  }
  int head = lane >> 4;
  float mh  = (head == 0) ? m0 : (head == 1) ? m1 : (head == 2) ? m2 : m3;
  float edh = (head == 0) ? edv.x : (head == 1) ? edv.y : (head == 2) ? edv.z : edv.w;

  // pass 2: weighted gather; lane owns channels 4*lane..4*lane+3
  float a0 = 0.f, a1 = 0.f, a2 = 0.f, a3 = 0.f, den = 0.f;
  for (int i = 0; i < deg; ++i){
    int s = srcs[base + i];
    float e = es[s * 4 + head] + edh;
    e = e > 0.f ? e : 0.2f * e;
    float w = __expf(e - mh);
    den += w;
    ushort4 hv = *(const ushort4*)(hb + (size_t)s * WIDTH + 4 * lane);
    a0 += w * b2f(hv.x);
    a1 += w * b2f(hv.y);
    a2 += w * b2f(hv.z);
    a3 += w * b2f(hv.w);
  }
  float inv = 1.0f / den;
  const float* bp = bias + 4 * lane;
  float o0 = fmaxf(a0 * inv + bp[0], 0.f);
  float o1 = fmaxf(a1 * inv + bp[1], 0.f);
  float o2 = fmaxf(a2 * inv + bp[2], 0.f);
  float o3 = fmaxf(a3 * inv + bp[3], 0.f);
  ushort4 o;
  o.x = f2bf(o0); o.y = f2bf(o1); o.z = f2bf(o2); o.w = f2bf(o3);
  *(ushort4*)(hout + (size_t)n * WIDTH + 4 * lane) = o;
}

// ---------------- output head: out[n][cls] = concat(h1,h2,h3)[n] . Wo[:,cls] + bo ----------------
#define NPB 120
__global__ __launch_bounds__(256) void out_head_kernel(const unsigned short* __restrict__ h1,
                                                       const unsigned short* __restrict__ h2,
                                                       const unsigned short* __restrict__ h3,
                                                       const float* __restrict__ Wo,
                                                       const float* __restrict__ bo,
                                                       float* __restrict__ out){
  __shared__ unsigned short WoLds[768 * NCLS];
  int tid = threadIdx.x;
  for (int i = tid; i < 768 * NCLS; i += 256) WoLds[i] = f2bf(Wo[i]);
  __syncthreads();
  int lane = tid & 63, wid = tid >> 6;
  int cl = lane < NCLS ? lane : NCLS - 1;
  int start = blockIdx.x * NPB;
  int end = start + NPB; if (end > N_NODES) end = N_NODES;
  for (int n = start + wid; n < end; n += 4){
    float a0 = 0.f, a1 = 0.f, a2 = 0.f, a3 = 0.f;
    const unsigned short* hr;
    #pragma unroll
    for (int part = 0; part < 3; ++part){
      hr = (part == 0) ? h1 + (size_t)n * WIDTH
         : (part == 1) ? h2 + (size_t)n * WIDTH
                       : h3 + (size_t)n * WIDTH;
      int cbase = part * WIDTH;
      for (int c = 0; c < WIDTH; c += 4){
        ushort4 hv = *(const ushort4*)(hr + c);
        int w0 = (cbase + c) * NCLS + cl;
        a0 += b2f(hv.x) * b2f(WoLds[w0]);
        a1 += b2f(hv.y) * b2f(WoLds[w0 + NCLS]);
        a2 += b2f(hv.z) * b2f(WoLds[w0 + 2 * NCLS]);
        a3 += b2f(hv.w) * b2f(WoLds[w0 + 3 * NCLS]);
      }
    }
    if (lane < NCLS) out[(size_t)n * NCLS + lane] = a0 + a1 + a2 + a3 + bo[lane];
  }
}

// ---------------- host launch ----------------
static inline size_t align256(size_t x){ return (x + 255) & ~(size_t)255; }

extern "C" void kernel_launch(void* const* d_in, const int* in_sizes, int n_in,
                              void* d_out, int out_size, void* d_ws, size_t ws_size,
                              hipStream_t stream) {
  const float* x   = (const float*)d_in[0];
  const int*   ei  = (const int*)  d_in[1];
  const float* W1  = (const float*)d_in[2];
  const float* as1 = (const float*)d_in[3];
  const float* ad1 = (const float*)d_in[4];
  const float* b1  = (const float*)d_in[5];
  const float* W2  = (const float*)d_in[6];
  const float* as2 = (const float*)d_in[7];
  const float* ad2 = (const float*)d_in[8];
  const float* b2  = (const float*)d_in[9];
  const float* W3  = (const float*)d_in[10];
  const float* as3 = (const float*)d_in[11];
  const float* ad3 = (const float*)d_in[12];
  const float* b3  = (const float*)d_in[13];
  const float* Wo  = (const float*)d_in[14];
  const float* bo  = (const float*)d_in[15];
  float* out = (float*)d_out;

  char* p = (char*)d_ws;
  auto take = [&](size_t bytes) -> char* { char* cur = p; p += align256(bytes); return cur; };

  unsigned short* xb    = (unsigned short*)take((size_t)N_NODES * F_IN * 2);
  unsigned short* Wt1   = (unsigned short*)take((size_t)WIDTH * F_IN * 2);
  unsigned short* Wt2   = (unsigned short*)take((size_t)WIDTH * WIDTH * 2);
  unsigned short* Wt3   = (unsigned short*)take((size_t)WIDTH * WIDTH * 2);
  float*          hpre  = (float*)take((size_t)N_NODES * WIDTH * 4);
  unsigned short* hpreb = (unsigned short*)take((size_t)N_NODES * WIDTH * 2);
  float*          es    = (float*)take((size_t)N_NODES * 4 * 4);
  float*          ed    = (float*)take((size_t)N_NODES * 4 * 4);
  unsigned short* h1b   = (unsigned short*)take((size_t)N_NODES * WIDTH * 2);
  unsigned short* h2b   = (unsigned short*)take((size_t)N_NODES * WIDTH * 2);
  unsigned short* h3b   = (unsigned short*)take((size_t)N_NODES * WIDTH * 2);
  int*            counts  = (int*)take((size_t)N_NODES * 4);
  int*            offsets = (int*)take((size_t)(N_NODES + 1) * 4);
  int*            cursor  = (int*)take((size_t)N_NODES * 4);
  int*            srcs    = (int*)take((size_t)ETOT * 4);

  // prep: casts + transposes
  cast4_kernel<<<(N_NODES * F_IN / 4 + 255) / 256, 256, 0, stream>>>(x, xb, N_NODES * F_IN / 4);
  transpose_w_kernel<<<dim3(F_IN / 256, WIDTH), 256, 0, stream>>>(W1, Wt1, F_IN, WIDTH);
  transpose_w_kernel<<<dim3(1, WIDTH), 256, 0, stream>>>(W2, Wt2, WIDTH, WIDTH);
  transpose_w_kernel<<<dim3(1, WIDTH), 256, 0, stream>>>(W3, Wt3, WIDTH, WIDTH);

  // CSR build
  zero_kernel<<<(N_NODES + 255) / 256, 256, 0, stream>>>(counts, N_NODES);
  hist_kernel<<<(ETOT + 255) / 256, 256, 0, stream>>>(ei, counts);
  scan_kernel<<<1, 1024, 0, stream>>>(counts, offsets, cursor, N_NODES);
  scatter_kernel<<<(ETOT + 255) / 256, 256, 0, stream>>>(ei, cursor, srcs);

  const int gemm_grid = (N_NODES + BM - 1) / BM;   // 469
  const int node_grid = N_NODES / 4;               // 7500

  // layer 1
  gemm_bf16_kernel<<<gemm_grid, 256, 0, stream>>>(xb, Wt1, hpre, N_NODES, F_IN);
  esed_kernel<<<node_grid, 256, 0, stream>>>(hpre, as1, ad1, es, ed, hpreb);
  agg_kernel<<<node_grid, 256, 0, stream>>>(offsets, srcs, es, ed, hpreb, b1, h1b);
  // layer 2
  gemm_bf16_kernel<<<gemm_grid, 256, 0, stream>>>(h1b, Wt2, hpre, N_NODES, WIDTH);
  esed_kernel<<<node_grid, 256, 0, stream>>>(hpre, as2, ad2, es, ed, hpreb);
  agg_kernel<<<node_grid, 256, 0, stream>>>(offsets, srcs, es, ed, hpreb, b2, h2b);
  // layer 3
  gemm_bf16_kernel<<<gemm_grid, 256, 0, stream>>>(h2b, Wt3, hpre, N_NODES, WIDTH);
  esed_kernel<<<node_grid, 256, 0, stream>>>(hpre, as3, ad3, es, ed, hpreb);
  agg_kernel<<<node_grid, 256, 0, stream>>>(offsets, srcs, es, ed, hpreb, b3, h3b);

  // output head
  out_head_kernel<<<(N_NODES + NPB - 1) / NPB, 256, 0, stream>>>(h1b, h2b, h3b, Wo, bo, out);
}

// Round 2
// 521.143 us; speedup vs baseline: 1.6204x; 1.6204x over previous
//
#include <hip/hip_runtime.h>

#define N_NODES 30000
#define N_EDGES 480000
#define ETOT    510000   // edges + self loops
#define F_IN    512
#define WIDTH   256
#define NCLS    40
#define KCAT    768      // WIDTH*3
#define NPAD    48       // NCLS padded to 3 MFMA col-tiles

typedef __attribute__((ext_vector_type(8))) short short8;
typedef __attribute__((ext_vector_type(4))) float f32x4;

__device__ __forceinline__ unsigned short f2bf(float f){
  unsigned u = __float_as_uint(f);
  u += 0x7fffu + ((u >> 16) & 1u);   // RTNE
  return (unsigned short)(u >> 16);
}
__device__ __forceinline__ float b2f(unsigned short s){
  return __uint_as_float(((unsigned)s) << 16);
}

// ---------------- cast x (f32 -> bf16), 4 elems/thread ----------------
__global__ void cast4_kernel(const float* __restrict__ in, unsigned short* __restrict__ out, int n4){
  int i = blockIdx.x * blockDim.x + threadIdx.x;
  if (i < n4){
    float4 v = *(const float4*)(in + 4*(size_t)i);
    ushort4 o;
    o.x = f2bf(v.x); o.y = f2bf(v.y); o.z = f2bf(v.z); o.w = f2bf(v.w);
    *(ushort4*)(out + 4*(size_t)i) = o;
  }
}

// ---------------- transpose W [K][Nc] f32 -> Wt [Nc][K] bf16 ----------------
__global__ void transpose_w_kernel(const float* __restrict__ W, unsigned short* __restrict__ Wt,
                                   int K, int Nc){
  int k = blockIdx.x * blockDim.x + threadIdx.x;
  int n = blockIdx.y;
  if (k < K) Wt[(size_t)n * K + k] = f2bf(W[(size_t)k * Nc + n]);
}

// ---------------- transpose+pad Wo [768][40] f32 -> WoT [48][768] bf16 ----------------
__global__ void transpose_wo_kernel(const float* __restrict__ Wo, unsigned short* __restrict__ WoT){
  int i = blockIdx.x * blockDim.x + threadIdx.x;   // i < 48*768
  if (i < NPAD * KCAT){
    int c = i / KCAT, k = i - c * KCAT;
    WoT[i] = (c < NCLS) ? f2bf(Wo[(size_t)k * NCLS + c]) : (unsigned short)0;
  }
}

// ---------------- CSR build ----------------
__global__ void zero_kernel(int* __restrict__ p, int n){
  int i = blockIdx.x * blockDim.x + threadIdx.x;
  if (i < n) p[i] = 0;
}

__global__ void hist_kernel(const int* __restrict__ ei, int* __restrict__ counts){
  int e = blockIdx.x * blockDim.x + threadIdx.x;
  if (e < ETOT){
    int d = (e < N_EDGES) ? ei[N_EDGES + e] : (e - N_EDGES);
    atomicAdd(&counts[d], 1);
  }
}

__global__ __launch_bounds__(1024) void scan_kernel(const int* __restrict__ counts,
                                                    int* __restrict__ offsets,
                                                    int* __restrict__ cursor, int n){
  __shared__ int wsum[16];
  int tid = threadIdx.x, lane = tid & 63, wid = tid >> 6;
  int running = 0;
  int nchunks = (n + 1023) >> 10;
  for (int ch = 0; ch < nchunks; ++ch){
    int i = (ch << 10) + tid;
    int v = (i < n) ? counts[i] : 0;
    int x = v;
    #pragma unroll
    for (int off = 1; off < 64; off <<= 1){
      int t = __shfl_up(x, off, 64);
      if (lane >= off) x += t;
    }
    if (lane == 63) wsum[wid] = x;
    __syncthreads();
    if (wid == 0){
      int s = (lane < 16) ? wsum[lane] : 0;
      #pragma unroll
      for (int off = 1; off < 16; off <<= 1){
        int t = __shfl_up(s, off, 64);
        if (lane >= off) s += t;
      }
      if (lane < 16) wsum[lane] = s;
    }
    __syncthreads();
    int waveprefix = (wid > 0) ? wsum[wid - 1] : 0;
    int excl = x - v + waveprefix + running;
    if (i < n){ offsets[i] = excl; cursor[i] = excl; }
    running += wsum[15];
    __syncthreads();
  }
  if (tid == 0) offsets[n] = running;
}

__global__ void scatter_kernel(const int* __restrict__ ei, int* __restrict__ cursor,
                               int* __restrict__ srcs){
  int e = blockIdx.x * blockDim.x + threadIdx.x;
  if (e < ETOT){
    int s, d;
    if (e < N_EDGES){ s = ei[e]; d = ei[N_EDGES + e]; }
    else { s = e - N_EDGES; d = s; }
    int pos = atomicAdd(&cursor[d], 1);
    srcs[pos] = s;
  }
}

// ---------------- bf16 MFMA GEMM: C[M][256] = A[M][K] @ B[K][256] ----------------
#define BM 64
#define BK 32
#define LDA 40   /* row stride in bf16 elems: 32 + 8 pad */

__global__ __launch_bounds__(256) void gemm_bf16_kernel(const unsigned short* __restrict__ A,
                                                        const unsigned short* __restrict__ Bt,
                                                        float* __restrict__ C,
                                                        int M, int K){
  __shared__ unsigned short Als[BM * LDA];
  __shared__ unsigned short Bls[256 * LDA];
  int tid = threadIdx.x;
  int lane = tid & 63, wid = tid >> 6;
  int l15 = lane & 15, quad = lane >> 4;
  int m0 = blockIdx.x * BM;

  f32x4 acc[16];
  #pragma unroll
  for (int t = 0; t < 16; ++t) acc[t] = (f32x4){0.f, 0.f, 0.f, 0.f};

  for (int k0 = 0; k0 < K; k0 += BK){
    __syncthreads();
    {
      int row = tid >> 2, g = tid & 3;
      int grow = m0 + row; if (grow >= M) grow = M - 1;
      uint4 av = *(const uint4*)(A + (size_t)grow * K + k0 + 8 * g);
      *(uint4*)(&Als[row * LDA + 8 * g]) = av;
      const unsigned short* src = Bt + (size_t)tid * K + k0;
      uint4 b0 = *(const uint4*)(src);
      uint4 b1 = *(const uint4*)(src + 8);
      uint4 b2 = *(const uint4*)(src + 16);
      uint4 b3 = *(const uint4*)(src + 24);
      unsigned short* dst = &Bls[tid * LDA];
      *(uint4*)(dst) = b0;
      *(uint4*)(dst + 8) = b1;
      *(uint4*)(dst + 16) = b2;
      *(uint4*)(dst + 24) = b3;
    }
    __syncthreads();
    short8 af = *(const short8*)(&Als[(16 * wid + l15) * LDA + quad * 8]);
    #pragma unroll
    for (int t = 0; t < 16; ++t){
      short8 bf = *(const short8*)(&Bls[(16 * t + l15) * LDA + quad * 8]);
      acc[t] = __builtin_amdgcn_mfma_f32_16x16x32_bf16(af, bf, acc[t], 0, 0, 0);
    }
  }

  int row0 = m0 + 16 * wid + quad * 4;
  #pragma unroll
  for (int t = 0; t < 16; ++t){
    int col = 16 * t + l15;
    #pragma unroll
    for (int r = 0; r < 4; ++r){
      int grow = row0 + r;
      if (grow < M) C[(size_t)grow * WIDTH + col] = acc[t][r];
    }
  }
}

// ---------------- es/ed + bf16 cast of h ----------------
__global__ __launch_bounds__(256) void esed_kernel(const float* __restrict__ hpre,
                                                   const float* __restrict__ a_s,
                                                   const float* __restrict__ a_d,
                                                   float* __restrict__ es, float* __restrict__ ed,
                                                   unsigned short* __restrict__ hb){
  int n = blockIdx.x * 4 + (threadIdx.x >> 6);
  int lane = threadIdx.x & 63;
  float4 h = *(const float4*)(hpre + (size_t)n * WIDTH + 4 * lane);
  int head = lane >> 4, cl = (lane & 15) * 4;
  float4 as = *(const float4*)(a_s + head * 64 + cl);
  float4 ad = *(const float4*)(a_d + head * 64 + cl);
  float ps = h.x * as.x + h.y * as.y + h.z * as.z + h.w * as.w;
  float pd = h.x * ad.x + h.y * ad.y + h.z * ad.z + h.w * ad.w;
  #pragma unroll
  for (int off = 1; off < 16; off <<= 1){
    ps += __shfl_xor(ps, off, 64);
    pd += __shfl_xor(pd, off, 64);
  }
  if ((lane & 15) == 0){
    es[n * 4 + head] = ps;
    ed[n * 4 + head] = pd;
  }
  ushort4 o;
  o.x = f2bf(h.x); o.y = f2bf(h.y); o.z = f2bf(h.z); o.w = f2bf(h.w);
  *(ushort4*)(hb + (size_t)n * WIDTH + 4 * lane) = o;
}

// ---------------- aggregation: wave per dst node, 2-pass segment softmax ----------------
__global__ __launch_bounds__(256) void agg_kernel(const int* __restrict__ offsets,
                                                  const int* __restrict__ srcs,
                                                  const float* __restrict__ es,
                                                  const float* __restrict__ ed,
                                                  const unsigned short* __restrict__ hb,
                                                  const float* __restrict__ bias,
                                                  unsigned short* __restrict__ hout){
  int n = blockIdx.x * 4 + (threadIdx.x >> 6);
  int lane = threadIdx.x & 63;
  int base = offsets[n];
  int deg = offsets[n + 1] - base;
  float4 edv = *(const float4*)(ed + n * 4);

  float m0 = -1e30f, m1 = -1e30f, m2 = -1e30f, m3 = -1e30f;
  for (int i = lane; i < deg; i += 64){
    int s = srcs[base + i];
    float4 ev = *(const float4*)(es + s * 4);
    float e0 = ev.x + edv.x, e1 = ev.y + edv.y, e2 = ev.z + edv.z, e3 = ev.w + edv.w;
    e0 = e0 > 0.f ? e0 : 0.2f * e0;
    e1 = e1 > 0.f ? e1 : 0.2f * e1;
    e2 = e2 > 0.f ? e2 : 0.2f * e2;
    e3 = e3 > 0.f ? e3 : 0.2f * e3;
    m0 = fmaxf(m0, e0); m1 = fmaxf(m1, e1); m2 = fmaxf(m2, e2); m3 = fmaxf(m3, e3);
  }
  #pragma unroll
  for (int off = 32; off; off >>= 1){
    m0 = fmaxf(m0, __shfl_xor(m0, off, 64));
    m1 = fmaxf(m1, __shfl_xor(m1, off, 64));
    m2 = fmaxf(m2, __shfl_xor(m2, off, 64));
    m3 = fmaxf(m3, __shfl_xor(m3, off, 64));
  }
  int head = lane >> 4;
  float mh  = (head == 0) ? m0 : (head == 1) ? m1 : (head == 2) ? m2 : m3;
  float edh = (head == 0) ? edv.x : (head == 1) ? edv.y : (head == 2) ? edv.z : edv.w;

  float a0 = 0.f, a1 = 0.f, a2 = 0.f, a3 = 0.f, den = 0.f;
  for (int i = 0; i < deg; ++i){
    int s = srcs[base + i];
    float e = es[s * 4 + head] + edh;
    e = e > 0.f ? e : 0.2f * e;
    float w = __expf(e - mh);
    den += w;
    ushort4 hv = *(const ushort4*)(hb + (size_t)s * WIDTH + 4 * lane);
    a0 += w * b2f(hv.x);
    a1 += w * b2f(hv.y);
    a2 += w * b2f(hv.z);
    a3 += w * b2f(hv.w);
  }
  float inv = 1.0f / den;
  const float* bp = bias + 4 * lane;
  float o0 = fmaxf(a0 * inv + bp[0], 0.f);
  float o1 = fmaxf(a1 * inv + bp[1], 0.f);
  float o2 = fmaxf(a2 * inv + bp[2], 0.f);
  float o3 = fmaxf(a3 * inv + bp[3], 0.f);
  ushort4 o;
  o.x = f2bf(o0); o.y = f2bf(o1); o.z = f2bf(o2); o.w = f2bf(o3);
  *(ushort4*)(hout + (size_t)n * WIDTH + 4 * lane) = o;
}

// ---------------- output head as MFMA GEMM ----------------
// out[30000][40] = concat(h1,h2,h3) @ Wo + bo.  WoT is bf16 [48][768] (padded).
// No LDS: A-fragments direct from h buffers, B-fragments from L2-resident WoT.
__global__ __launch_bounds__(256) void out_gemm_kernel(const unsigned short* __restrict__ h1,
                                                       const unsigned short* __restrict__ h2,
                                                       const unsigned short* __restrict__ h3,
                                                       const unsigned short* __restrict__ WoT,
                                                       const float* __restrict__ bo,
                                                       float* __restrict__ out){
  int tid = threadIdx.x, lane = tid & 63, wid = tid >> 6;
  int l15 = lane & 15, quad = lane >> 4;
  int m0 = blockIdx.x * 64 + 16 * wid;        // 16-row tile per wave

  f32x4 acc[3];
  #pragma unroll
  for (int t = 0; t < 3; ++t) acc[t] = (f32x4){0.f, 0.f, 0.f, 0.f};

  int arow = m0 + l15; if (arow >= N_NODES) arow = N_NODES - 1;

  #pragma unroll
  for (int part = 0; part < 3; ++part){
    const unsigned short* hp = (part == 0) ? h1 : (part == 1) ? h2 : h3;
    const unsigned short* ap = hp + (size_t)arow * WIDTH;
    #pragma unroll
    for (int k0 = 0; k0 < WIDTH; k0 += 32){
      short8 af = *(const short8*)(ap + k0 + quad * 8);
      int kk = part * WIDTH + k0;
      #pragma unroll
      for (int t = 0; t < 3; ++t){
        short8 bf = *(const short8*)(WoT + (size_t)(16 * t + l15) * KCAT + kk + quad * 8);
        acc[t] = __builtin_amdgcn_mfma_f32_16x16x32_bf16(af, bf, acc[t], 0, 0, 0);
      }
    }
  }

  int r0 = m0 + quad * 4;
  #pragma unroll
  for (int t = 0; t < 3; ++t){
    int col = 16 * t + l15;
    if (col < NCLS){
      float bc = bo[col];
      #pragma unroll
      for (int r = 0; r < 4; ++r){
        int grow = r0 + r;
        if (grow < N_NODES) out[(size_t)grow * NCLS + col] = acc[t][r] + bc;
      }
    }
  }
}

// ---------------- host launch ----------------
static inline size_t align256(size_t x){ return (x + 255) & ~(size_t)255; }

extern "C" void kernel_launch(void* const* d_in, const int* in_sizes, int n_in,
                              void* d_out, int out_size, void* d_ws, size_t ws_size,
                              hipStream_t stream) {
  const float* x   = (const float*)d_in[0];
  const int*   ei  = (const int*)  d_in[1];
  const float* W1  = (const float*)d_in[2];
  const float* as1 = (const float*)d_in[3];
  const float* ad1 = (const float*)d_in[4];
  const float* b1  = (const float*)d_in[5];
  const float* W2  = (const float*)d_in[6];
  const float* as2 = (const float*)d_in[7];
  const float* ad2 = (const float*)d_in[8];
  const float* b2  = (const float*)d_in[9];
  const float* W3  = (const float*)d_in[10];
  const float* as3 = (const float*)d_in[11];
  const float* ad3 = (const float*)d_in[12];
  const float* b3  = (const float*)d_in[13];
  const float* Wo  = (const float*)d_in[14];
  const float* bo  = (const float*)d_in[15];
  float* out = (float*)d_out;

  char* p = (char*)d_ws;
  auto take = [&](size_t bytes) -> char* { char* cur = p; p += align256(bytes); return cur; };

  unsigned short* xb    = (unsigned short*)take((size_t)N_NODES * F_IN * 2);
  unsigned short* Wt1   = (unsigned short*)take((size_t)WIDTH * F_IN * 2);
  unsigned short* Wt2   = (unsigned short*)take((size_t)WIDTH * WIDTH * 2);
  unsigned short* Wt3   = (unsigned short*)take((size_t)WIDTH * WIDTH * 2);
  unsigned short* WoT   = (unsigned short*)take((size_t)NPAD * KCAT * 2);
  float*          hpre  = (float*)take((size_t)N_NODES * WIDTH * 4);
  unsigned short* hpreb = (unsigned short*)take((size_t)N_NODES * WIDTH * 2);
  float*          es    = (float*)take((size_t)N_NODES * 4 * 4);
  float*          ed    = (float*)take((size_t)N_NODES * 4 * 4);
  unsigned short* h1b   = (unsigned short*)take((size_t)N_NODES * WIDTH * 2);
  unsigned short* h2b   = (unsigned short*)take((size_t)N_NODES * WIDTH * 2);
  unsigned short* h3b   = (unsigned short*)take((size_t)N_NODES * WIDTH * 2);
  int*            counts  = (int*)take((size_t)N_NODES * 4);
  int*            offsets = (int*)take((size_t)(N_NODES + 1) * 4);
  int*            cursor  = (int*)take((size_t)N_NODES * 4);
  int*            srcs    = (int*)take((size_t)ETOT * 4);

  // prep: casts + transposes
  cast4_kernel<<<(N_NODES * F_IN / 4 + 255) / 256, 256, 0, stream>>>(x, xb, N_NODES * F_IN / 4);
  transpose_w_kernel<<<dim3(F_IN / 256, WIDTH), 256, 0, stream>>>(W1, Wt1, F_IN, WIDTH);
  transpose_w_kernel<<<dim3(1, WIDTH), 256, 0, stream>>>(W2, Wt2, WIDTH, WIDTH);
  transpose_w_kernel<<<dim3(1, WIDTH), 256, 0, stream>>>(W3, Wt3, WIDTH, WIDTH);
  transpose_wo_kernel<<<(NPAD * KCAT + 255) / 256, 256, 0, stream>>>(Wo, WoT);

  // CSR build
  zero_kernel<<<(N_NODES + 255) / 256, 256, 0, stream>>>(counts, N_NODES);
  hist_kernel<<<(ETOT + 255) / 256, 256, 0, stream>>>(ei, counts);
  scan_kernel<<<1, 1024, 0, stream>>>(counts, offsets, cursor, N_NODES);
  scatter_kernel<<<(ETOT + 255) / 256, 256, 0, stream>>>(ei, cursor, srcs);

  const int gemm_grid = (N_NODES + BM - 1) / BM;   // 469
  const int node_grid = N_NODES / 4;               // 7500

  // layer 1
  gemm_bf16_kernel<<<gemm_grid, 256, 0, stream>>>(xb, Wt1, hpre, N_NODES, F_IN);
  esed_kernel<<<node_grid, 256, 0, stream>>>(hpre, as1, ad1, es, ed, hpreb);
  agg_kernel<<<node_grid, 256, 0, stream>>>(offsets, srcs, es, ed, hpreb, b1, h1b);
  // layer 2
  gemm_bf16_kernel<<<gemm_grid, 256, 0, stream>>>(h1b, Wt2, hpre, N_NODES, WIDTH);
  esed_kernel<<<node_grid, 256, 0, stream>>>(hpre, as2, ad2, es, ed, hpreb);
  agg_kernel<<<node_grid, 256, 0, stream>>>(offsets, srcs, es, ed, hpreb, b2, h2b);
  // layer 3
  gemm_bf16_kernel<<<gemm_grid, 256, 0, stream>>>(h2b, Wt3, hpre, N_NODES, WIDTH);
  esed_kernel<<<node_grid, 256, 0, stream>>>(hpre, as3, ad3, es, ed, hpreb);
  agg_kernel<<<node_grid, 256, 0, stream>>>(offsets, srcs, es, ed, hpreb, b3, h3b);

  // output head (MFMA GEMM)
  out_gemm_kernel<<<gemm_grid, 256, 0, stream>>>(h1b, h2b, h3b, WoT, bo, out);
}

// Round 3
// 435.460 us; speedup vs baseline: 1.9392x; 1.1968x over previous
//
#include <hip/hip_runtime.h>

#define N_NODES 30000
#define N_EDGES 480000
#define ETOT    510000   // edges + self loops
#define F_IN    512
#define WIDTH   256
#define NCLS    40
#define KCAT    768      // WIDTH*3
#define NPAD    48       // NCLS padded to 3 MFMA col-tiles

typedef __attribute__((ext_vector_type(8))) short short8;
typedef __attribute__((ext_vector_type(4))) float f32x4;

__device__ __forceinline__ unsigned short f2bf(float f){
  unsigned u = __float_as_uint(f);
  u += 0x7fffu + ((u >> 16) & 1u);   // RTNE
  return (unsigned short)(u >> 16);
}
__device__ __forceinline__ float b2f(unsigned short s){
  return __uint_as_float(((unsigned)s) << 16);
}

// ---------------- cast x (f32 -> bf16), 4 elems/thread ----------------
__global__ void cast4_kernel(const float* __restrict__ in, unsigned short* __restrict__ out, int n4){
  int i = blockIdx.x * blockDim.x + threadIdx.x;
  if (i < n4){
    float4 v = *(const float4*)(in + 4*(size_t)i);
    ushort4 o;
    o.x = f2bf(v.x); o.y = f2bf(v.y); o.z = f2bf(v.z); o.w = f2bf(v.w);
    *(ushort4*)(out + 4*(size_t)i) = o;
  }
}

// ---------------- transpose W [K][Nc] f32 -> Wt [Nc][K] bf16 ----------------
__global__ void transpose_w_kernel(const float* __restrict__ W, unsigned short* __restrict__ Wt,
                                   int K, int Nc){
  int k = blockIdx.x * blockDim.x + threadIdx.x;
  int n = blockIdx.y;
  if (k < K) Wt[(size_t)n * K + k] = f2bf(W[(size_t)k * Nc + n]);
}

// ---------------- transpose+pad Wo [768][40] f32 -> WoT [48][768] bf16 ----------------
__global__ void transpose_wo_kernel(const float* __restrict__ Wo, unsigned short* __restrict__ WoT){
  int i = blockIdx.x * blockDim.x + threadIdx.x;   // i < 48*768
  if (i < NPAD * KCAT){
    int c = i / KCAT, k = i - c * KCAT;
    WoT[i] = (c < NCLS) ? f2bf(Wo[(size_t)k * NCLS + c]) : (unsigned short)0;
  }
}

// ---------------- CSR build ----------------
__global__ void zero_kernel(int* __restrict__ p, int n){
  int i = blockIdx.x * blockDim.x + threadIdx.x;
  if (i < n) p[i] = 0;
}

__global__ void hist_kernel(const int* __restrict__ ei, int* __restrict__ counts){
  int e = blockIdx.x * blockDim.x + threadIdx.x;
  if (e < ETOT){
    int d = (e < N_EDGES) ? ei[N_EDGES + e] : (e - N_EDGES);
    atomicAdd(&counts[d], 1);
  }
}

__global__ __launch_bounds__(1024) void scan_kernel(const int* __restrict__ counts,
                                                    int* __restrict__ offsets,
                                                    int* __restrict__ cursor, int n){
  __shared__ int wsum[16];
  int tid = threadIdx.x, lane = tid & 63, wid = tid >> 6;
  int running = 0;
  int nchunks = (n + 1023) >> 10;
  for (int ch = 0; ch < nchunks; ++ch){
    int i = (ch << 10) + tid;
    int v = (i < n) ? counts[i] : 0;
    int x = v;
    #pragma unroll
    for (int off = 1; off < 64; off <<= 1){
      int t = __shfl_up(x, off, 64);
      if (lane >= off) x += t;
    }
    if (lane == 63) wsum[wid] = x;
    __syncthreads();
    if (wid == 0){
      int s = (lane < 16) ? wsum[lane] : 0;
      #pragma unroll
      for (int off = 1; off < 16; off <<= 1){
        int t = __shfl_up(s, off, 64);
        if (lane >= off) s += t;
      }
      if (lane < 16) wsum[lane] = s;
    }
    __syncthreads();
    int waveprefix = (wid > 0) ? wsum[wid - 1] : 0;
    int excl = x - v + waveprefix + running;
    if (i < n){ offsets[i] = excl; cursor[i] = excl; }
    running += wsum[15];
    __syncthreads();
  }
  if (tid == 0) offsets[n] = running;
}

__global__ void scatter_kernel(const int* __restrict__ ei, int* __restrict__ cursor,
                               int* __restrict__ srcs){
  int e = blockIdx.x * blockDim.x + threadIdx.x;
  if (e < ETOT){
    int s, d;
    if (e < N_EDGES){ s = ei[e]; d = ei[N_EDGES + e]; }
    else { s = e - N_EDGES; d = s; }
    int pos = atomicAdd(&cursor[d], 1);
    srcs[pos] = s;
  }
}

// ---------------- bf16 MFMA GEMM: C[M][256] = A[M][K] @ B[K][256] ----------------
#define BM 64
#define BK 32
#define LDA 40   /* row stride in bf16 elems: 32 + 8 pad */

__global__ __launch_bounds__(256) void gemm_bf16_kernel(const unsigned short* __restrict__ A,
                                                        const unsigned short* __restrict__ Bt,
                                                        float* __restrict__ C,
                                                        int M, int K){
  __shared__ unsigned short Als[BM * LDA];
  __shared__ unsigned short Bls[256 * LDA];
  int tid = threadIdx.x;
  int lane = tid & 63, wid = tid >> 6;
  int l15 = lane & 15, quad = lane >> 4;
  int m0 = blockIdx.x * BM;

  f32x4 acc[16];
  #pragma unroll
  for (int t = 0; t < 16; ++t) acc[t] = (f32x4){0.f, 0.f, 0.f, 0.f};

  for (int k0 = 0; k0 < K; k0 += BK){
    __syncthreads();
    {
      int row = tid >> 2, g = tid & 3;
      int grow = m0 + row; if (grow >= M) grow = M - 1;
      uint4 av = *(const uint4*)(A + (size_t)grow * K + k0 + 8 * g);
      *(uint4*)(&Als[row * LDA + 8 * g]) = av;
      const unsigned short* src = Bt + (size_t)tid * K + k0;
      uint4 b0 = *(const uint4*)(src);
      uint4 b1 = *(const uint4*)(src + 8);
      uint4 b2 = *(const uint4*)(src + 16);
      uint4 b3 = *(const uint4*)(src + 24);
      unsigned short* dst = &Bls[tid * LDA];
      *(uint4*)(dst) = b0;
      *(uint4*)(dst + 8) = b1;
      *(uint4*)(dst + 16) = b2;
      *(uint4*)(dst + 24) = b3;
    }
    __syncthreads();
    short8 af = *(const short8*)(&Als[(16 * wid + l15) * LDA + quad * 8]);
    #pragma unroll
    for (int t = 0; t < 16; ++t){
      short8 bf = *(const short8*)(&Bls[(16 * t + l15) * LDA + quad * 8]);
      acc[t] = __builtin_amdgcn_mfma_f32_16x16x32_bf16(af, bf, acc[t], 0, 0, 0);
    }
  }

  int row0 = m0 + 16 * wid + quad * 4;
  #pragma unroll
  for (int t = 0; t < 16; ++t){
    int col = 16 * t + l15;
    #pragma unroll
    for (int r = 0; r < 4; ++r){
      int grow = row0 + r;
      if (grow < M) C[(size_t)grow * WIDTH + col] = acc[t][r];
    }
  }
}

// ---------------- es/ed + bf16 cast of h ----------------
__global__ __launch_bounds__(256) void esed_kernel(const float* __restrict__ hpre,
                                                   const float* __restrict__ a_s,
                                                   const float* __restrict__ a_d,
                                                   float* __restrict__ es, float* __restrict__ ed,
                                                   unsigned short* __restrict__ hb){
  int n = blockIdx.x * 4 + (threadIdx.x >> 6);
  int lane = threadIdx.x & 63;
  float4 h = *(const float4*)(hpre + (size_t)n * WIDTH + 4 * lane);
  int head = lane >> 4, cl = (lane & 15) * 4;
  float4 as = *(const float4*)(a_s + head * 64 + cl);
  float4 ad = *(const float4*)(a_d + head * 64 + cl);
  float ps = h.x * as.x + h.y * as.y + h.z * as.z + h.w * as.w;
  float pd = h.x * ad.x + h.y * ad.y + h.z * ad.z + h.w * ad.w;
  #pragma unroll
  for (int off = 1; off < 16; off <<= 1){
    ps += __shfl_xor(ps, off, 64);
    pd += __shfl_xor(pd, off, 64);
  }
  if ((lane & 15) == 0){
    es[n * 4 + head] = ps;
    ed[n * 4 + head] = pd;
  }
  ushort4 o;
  o.x = f2bf(h.x); o.y = f2bf(h.y); o.z = f2bf(h.z); o.w = f2bf(h.w);
  *(ushort4*)(hb + (size_t)n * WIDTH + 4 * lane) = o;
}

// ---------------- aggregation: wave per dst node, 2-pass segment softmax ----------------
// Half-wave edge split: lanes 0-31 = even slot, 32-63 = odd slot; lane owns 8 channels (16B).
// 4-slot unroll -> 8 edges in flight/iter. Pass-1 caches leaky(e) per edge in LDS.
__global__ __launch_bounds__(256) void agg_kernel(const int* __restrict__ offsets,
                                                  const int* __restrict__ srcs,
                                                  const float* __restrict__ es,
                                                  const float* __restrict__ ed,
                                                  const unsigned short* __restrict__ hb,
                                                  const float* __restrict__ bias,
                                                  unsigned short* __restrict__ hout){
  __shared__ float eLds[4][64][4];
  int wid = threadIdx.x >> 6;
  int n = blockIdx.x * 4 + wid;
  int lane = threadIdx.x & 63;
  int half = lane >> 5, l32 = lane & 31;
  int base = offsets[n];
  int deg = offsets[n + 1] - base;
  float4 edv = *(const float4*)(ed + n * 4);

  // pass 1: per-head max of leaky(es[src]+ed[n]); cache leaky(e) for edges <64 in LDS
  float m0 = -1e30f, m1 = -1e30f, m2 = -1e30f, m3 = -1e30f;
  for (int i = lane; i < deg; i += 64){
    int s = srcs[base + i];
    float4 ev = *(const float4*)(es + s * 4);
    float e0 = ev.x + edv.x, e1 = ev.y + edv.y, e2 = ev.z + edv.z, e3 = ev.w + edv.w;
    e0 = e0 > 0.f ? e0 : 0.2f * e0;
    e1 = e1 > 0.f ? e1 : 0.2f * e1;
    e2 = e2 > 0.f ? e2 : 0.2f * e2;
    e3 = e3 > 0.f ? e3 : 0.2f * e3;
    if (i < 64) *(float4*)(&eLds[wid][i][0]) = (float4){e0, e1, e2, e3};
    m0 = fmaxf(m0, e0); m1 = fmaxf(m1, e1); m2 = fmaxf(m2, e2); m3 = fmaxf(m3, e3);
  }
  #pragma unroll
  for (int off = 32; off; off >>= 1){
    m0 = fmaxf(m0, __shfl_xor(m0, off, 64));
    m1 = fmaxf(m1, __shfl_xor(m1, off, 64));
    m2 = fmaxf(m2, __shfl_xor(m2, off, 64));
    m3 = fmaxf(m3, __shfl_xor(m3, off, 64));
  }
  int head = l32 >> 3;                       // 8 lanes per head, 8 ch/lane
  float mh  = (head == 0) ? m0 : (head == 1) ? m1 : (head == 2) ? m2 : m3;
  float edh = (head == 0) ? edv.x : (head == 1) ? edv.y : (head == 2) ? edv.z : edv.w;

  // pass 2: weighted gather, 8 edges (4 per half) per iteration
  float a0=0.f,a1=0.f,a2=0.f,a3=0.f,a4=0.f,a5=0.f,a6=0.f,a7=0.f;
  float den = 0.f;
  const unsigned short* hcol = hb + 8 * l32;
  for (int i = 0; i < deg; i += 8){
    int sidx[4]; float w[4];
    #pragma unroll
    for (int u = 0; u < 4; ++u){
      int idx = i + 2 * u + half;
      bool v = idx < deg;
      sidx[u] = srcs[base + (v ? idx : 0)];
      float le;
      if (idx < 64){
        le = eLds[wid][v ? idx : 0][head];
      } else {
        float e = es[sidx[u] * 4 + head] + edh;
        le = e > 0.f ? e : 0.2f * e;
      }
      w[u] = v ? __expf(le - mh) : 0.f;
    }
    uint4 hv[4];
    #pragma unroll
    for (int u = 0; u < 4; ++u)
      hv[u] = *(const uint4*)(hcol + (size_t)sidx[u] * WIDTH);
    #pragma unroll
    for (int u = 0; u < 4; ++u){
      float wu = w[u];
      den += wu;
      a0 += wu * b2f((unsigned short)(hv[u].x & 0xffff));
      a1 += wu * b2f((unsigned short)(hv[u].x >> 16));
      a2 += wu * b2f((unsigned short)(hv[u].y & 0xffff));
      a3 += wu * b2f((unsigned short)(hv[u].y >> 16));
      a4 += wu * b2f((unsigned short)(hv[u].z & 0xffff));
      a5 += wu * b2f((unsigned short)(hv[u].z >> 16));
      a6 += wu * b2f((unsigned short)(hv[u].w & 0xffff));
      a7 += wu * b2f((unsigned short)(hv[u].w >> 16));
    }
  }
  // combine the two halves
  den += __shfl_xor(den, 32, 64);
  a0 += __shfl_xor(a0, 32, 64); a1 += __shfl_xor(a1, 32, 64);
  a2 += __shfl_xor(a2, 32, 64); a3 += __shfl_xor(a3, 32, 64);
  a4 += __shfl_xor(a4, 32, 64); a5 += __shfl_xor(a5, 32, 64);
  a6 += __shfl_xor(a6, 32, 64); a7 += __shfl_xor(a7, 32, 64);

  if (half == 0){
    float inv = 1.0f / den;
    const float* bp = bias + 8 * l32;
    float4 bv0 = *(const float4*)(bp);
    float4 bv1 = *(const float4*)(bp + 4);
    float o0 = fmaxf(a0 * inv + bv0.x, 0.f);
    float o1 = fmaxf(a1 * inv + bv0.y, 0.f);
    float o2 = fmaxf(a2 * inv + bv0.z, 0.f);
    float o3 = fmaxf(a3 * inv + bv0.w, 0.f);
    float o4 = fmaxf(a4 * inv + bv1.x, 0.f);
    float o5 = fmaxf(a5 * inv + bv1.y, 0.f);
    float o6 = fmaxf(a6 * inv + bv1.z, 0.f);
    float o7 = fmaxf(a7 * inv + bv1.w, 0.f);
    uint4 o;
    o.x = (unsigned)f2bf(o0) | ((unsigned)f2bf(o1) << 16);
    o.y = (unsigned)f2bf(o2) | ((unsigned)f2bf(o3) << 16);
    o.z = (unsigned)f2bf(o4) | ((unsigned)f2bf(o5) << 16);
    o.w = (unsigned)f2bf(o6) | ((unsigned)f2bf(o7) << 16);
    *(uint4*)(hout + (size_t)n * WIDTH + 8 * l32) = o;
  }
}

// ---------------- output head as MFMA GEMM ----------------
__global__ __launch_bounds__(256) void out_gemm_kernel(const unsigned short* __restrict__ h1,
                                                       const unsigned short* __restrict__ h2,
                                                       const unsigned short* __restrict__ h3,
                                                       const unsigned short* __restrict__ WoT,
                                                       const float* __restrict__ bo,
                                                       float* __restrict__ out){
  int tid = threadIdx.x, lane = tid & 63, wid = tid >> 6;
  int l15 = lane & 15, quad = lane >> 4;
  int m0 = blockIdx.x * 64 + 16 * wid;

  f32x4 acc[3];
  #pragma unroll
  for (int t = 0; t < 3; ++t) acc[t] = (f32x4){0.f, 0.f, 0.f, 0.f};

  int arow = m0 + l15; if (arow >= N_NODES) arow = N_NODES - 1;

  #pragma unroll
  for (int part = 0; part < 3; ++part){
    const unsigned short* hp = (part == 0) ? h1 : (part == 1) ? h2 : h3;
    const unsigned short* ap = hp + (size_t)arow * WIDTH;
    #pragma unroll
    for (int k0 = 0; k0 < WIDTH; k0 += 32){
      short8 af = *(const short8*)(ap + k0 + quad * 8);
      int kk = part * WIDTH + k0;
      #pragma unroll
      for (int t = 0; t < 3; ++t){
        short8 bf = *(const short8*)(WoT + (size_t)(16 * t + l15) * KCAT + kk + quad * 8);
        acc[t] = __builtin_amdgcn_mfma_f32_16x16x32_bf16(af, bf, acc[t], 0, 0, 0);
      }
    }
  }

  int r0 = m0 + quad * 4;
  #pragma unroll
  for (int t = 0; t < 3; ++t){
    int col = 16 * t + l15;
    if (col < NCLS){
      float bc = bo[col];
      #pragma unroll
      for (int r = 0; r < 4; ++r){
        int grow = r0 + r;
        if (grow < N_NODES) out[(size_t)grow * NCLS + col] = acc[t][r] + bc;
      }
    }
  }
}

// ---------------- host launch ----------------
static inline size_t align256(size_t x){ return (x + 255) & ~(size_t)255; }

extern "C" void kernel_launch(void* const* d_in, const int* in_sizes, int n_in,
                              void* d_out, int out_size, void* d_ws, size_t ws_size,
                              hipStream_t stream) {
  const float* x   = (const float*)d_in[0];
  const int*   ei  = (const int*)  d_in[1];
  const float* W1  = (const float*)d_in[2];
  const float* as1 = (const float*)d_in[3];
  const float* ad1 = (const float*)d_in[4];
  const float* b1  = (const float*)d_in[5];
  const float* W2  = (const float*)d_in[6];
  const float* as2 = (const float*)d_in[7];
  const float* ad2 = (const float*)d_in[8];
  const float* b2  = (const float*)d_in[9];
  const float* W3  = (const float*)d_in[10];
  const float* as3 = (const float*)d_in[11];
  const float* ad3 = (const float*)d_in[12];
  const float* b3  = (const float*)d_in[13];
  const float* Wo  = (const float*)d_in[14];
  const float* bo  = (const float*)d_in[15];
  float* out = (float*)d_out;

  char* p = (char*)d_ws;
  auto take = [&](size_t bytes) -> char* { char* cur = p; p += align256(bytes); return cur; };

  unsigned short* xb    = (unsigned short*)take((size_t)N_NODES * F_IN * 2);
  unsigned short* Wt1   = (unsigned short*)take((size_t)WIDTH * F_IN * 2);
  unsigned short* Wt2   = (unsigned short*)take((size_t)WIDTH * WIDTH * 2);
  unsigned short* Wt3   = (unsigned short*)take((size_t)WIDTH * WIDTH * 2);
  unsigned short* WoT   = (unsigned short*)take((size_t)NPAD * KCAT * 2);
  float*          hpre  = (float*)take((size_t)N_NODES * WIDTH * 4);
  unsigned short* hpreb = (unsigned short*)take((size_t)N_NODES * WIDTH * 2);
  float*          es    = (float*)take((size_t)N_NODES * 4 * 4);
  float*          ed    = (float*)take((size_t)N_NODES * 4 * 4);
  unsigned short* h1b   = (unsigned short*)take((size_t)N_NODES * WIDTH * 2);
  unsigned short* h2b   = (unsigned short*)take((size_t)N_NODES * WIDTH * 2);
  unsigned short* h3b   = (unsigned short*)take((size_t)N_NODES * WIDTH * 2);
  int*            counts  = (int*)take((size_t)N_NODES * 4);
  int*            offsets = (int*)take((size_t)(N_NODES + 1) * 4);
  int*            cursor  = (int*)take((size_t)N_NODES * 4);
  int*            srcs    = (int*)take((size_t)ETOT * 4);

  // prep: casts + transposes
  cast4_kernel<<<(N_NODES * F_IN / 4 + 255) / 256, 256, 0, stream>>>(x, xb, N_NODES * F_IN / 4);
  transpose_w_kernel<<<dim3(F_IN / 256, WIDTH), 256, 0, stream>>>(W1, Wt1, F_IN, WIDTH);
  transpose_w_kernel<<<dim3(1, WIDTH), 256, 0, stream>>>(W2, Wt2, WIDTH, WIDTH);
  transpose_w_kernel<<<dim3(1, WIDTH), 256, 0, stream>>>(W3, Wt3, WIDTH, WIDTH);
  transpose_wo_kernel<<<(NPAD * KCAT + 255) / 256, 256, 0, stream>>>(Wo, WoT);

  // CSR build
  zero_kernel<<<(N_NODES + 255) / 256, 256, 0, stream>>>(counts, N_NODES);
  hist_kernel<<<(ETOT + 255) / 256, 256, 0, stream>>>(ei, counts);
  scan_kernel<<<1, 1024, 0, stream>>>(counts, offsets, cursor, N_NODES);
  scatter_kernel<<<(ETOT + 255) / 256, 256, 0, stream>>>(ei, cursor, srcs);

  const int gemm_grid = (N_NODES + BM - 1) / BM;   // 469
  const int node_grid = N_NODES / 4;               // 7500

  // layer 1
  gemm_bf16_kernel<<<gemm_grid, 256, 0, stream>>>(xb, Wt1, hpre, N_NODES, F_IN);
  esed_kernel<<<node_grid, 256, 0, stream>>>(hpre, as1, ad1, es, ed, hpreb);
  agg_kernel<<<node_grid, 256, 0, stream>>>(offsets, srcs, es, ed, hpreb, b1, h1b);
  // layer 2
  gemm_bf16_kernel<<<gemm_grid, 256, 0, stream>>>(h1b, Wt2, hpre, N_NODES, WIDTH);
  esed_kernel<<<node_grid, 256, 0, stream>>>(hpre, as2, ad2, es, ed, hpreb);
  agg_kernel<<<node_grid, 256, 0, stream>>>(offsets, srcs, es, ed, hpreb, b2, h2b);
  // layer 3
  gemm_bf16_kernel<<<gemm_grid, 256, 0, stream>>>(h2b, Wt3, hpre, N_NODES, WIDTH);
  esed_kernel<<<node_grid, 256, 0, stream>>>(hpre, as3, ad3, es, ed, hpreb);
  agg_kernel<<<node_grid, 256, 0, stream>>>(offsets, srcs, es, ed, hpreb, b3, h3b);

  // output head (MFMA GEMM)
  out_gemm_kernel<<<gemm_grid, 256, 0, stream>>>(h1b, h2b, h3b, WoT, bo, out);
}

// Round 4
// 411.604 us; speedup vs baseline: 2.0516x; 1.0580x over previous
//
#include <hip/hip_runtime.h>

#define N_NODES 30000
#define N_EDGES 480000
#define ETOT    510000   // edges + self loops
#define F_IN    512
#define WIDTH   256
#define NCLS    40
#define KCAT    768      // WIDTH*3
#define NPAD    48       // NCLS padded to 3 MFMA col-tiles

typedef __attribute__((ext_vector_type(8))) short short8;
typedef __attribute__((ext_vector_type(4))) float f32x4;

__device__ __forceinline__ unsigned short f2bf(float f){
  unsigned u = __float_as_uint(f);
  u += 0x7fffu + ((u >> 16) & 1u);   // RTNE
  return (unsigned short)(u >> 16);
}
__device__ __forceinline__ float b2f(unsigned short s){
  return __uint_as_float(((unsigned)s) << 16);
}

// ---------------- transpose W [K][Nc] f32 -> Wt [Nc][K] bf16 ----------------
__global__ void transpose_w_kernel(const float* __restrict__ W, unsigned short* __restrict__ Wt,
                                   int K, int Nc){
  int k = blockIdx.x * blockDim.x + threadIdx.x;
  int n = blockIdx.y;
  if (k < K) Wt[(size_t)n * K + k] = f2bf(W[(size_t)k * Nc + n]);
}

// ---------------- transpose+pad Wo [768][40] f32 -> WoT [48][768] bf16 ----------------
__global__ void transpose_wo_kernel(const float* __restrict__ Wo, unsigned short* __restrict__ WoT){
  int i = blockIdx.x * blockDim.x + threadIdx.x;   // i < 48*768
  if (i < NPAD * KCAT){
    int c = i / KCAT, k = i - c * KCAT;
    WoT[i] = (c < NCLS) ? f2bf(Wo[(size_t)k * NCLS + c]) : (unsigned short)0;
  }
}

// ---------------- CSR build ----------------
__global__ void zero_kernel(int* __restrict__ p, int n){
  int i = blockIdx.x * blockDim.x + threadIdx.x;
  if (i < n) p[i] = 0;
}

__global__ void hist_kernel(const int* __restrict__ ei, int* __restrict__ counts){
  int e = blockIdx.x * blockDim.x + threadIdx.x;
  if (e < ETOT){
    int d = (e < N_EDGES) ? ei[N_EDGES + e] : (e - N_EDGES);
    atomicAdd(&counts[d], 1);
  }
}

__global__ __launch_bounds__(1024) void scan_kernel(const int* __restrict__ counts,
                                                    int* __restrict__ offsets,
                                                    int* __restrict__ cursor, int n){
  __shared__ int wsum[16];
  int tid = threadIdx.x, lane = tid & 63, wid = tid >> 6;
  int running = 0;
  int nchunks = (n + 1023) >> 10;
  for (int ch = 0; ch < nchunks; ++ch){
    int i = (ch << 10) + tid;
    int v = (i < n) ? counts[i] : 0;
    int x = v;
    #pragma unroll
    for (int off = 1; off < 64; off <<= 1){
      int t = __shfl_up(x, off, 64);
      if (lane >= off) x += t;
    }
    if (lane == 63) wsum[wid] = x;
    __syncthreads();
    if (wid == 0){
      int s = (lane < 16) ? wsum[lane] : 0;
      #pragma unroll
      for (int off = 1; off < 16; off <<= 1){
        int t = __shfl_up(s, off, 64);
        if (lane >= off) s += t;
      }
      if (lane < 16) wsum[lane] = s;
    }
    __syncthreads();
    int waveprefix = (wid > 0) ? wsum[wid - 1] : 0;
    int excl = x - v + waveprefix + running;
    if (i < n){ offsets[i] = excl; cursor[i] = excl; }
    running += wsum[15];
    __syncthreads();
  }
  if (tid == 0) offsets[n] = running;
}

__global__ void scatter_kernel(const int* __restrict__ ei, int* __restrict__ cursor,
                               int* __restrict__ srcs){
  int e = blockIdx.x * blockDim.x + threadIdx.x;
  if (e < ETOT){
    int s, d;
    if (e < N_EDGES){ s = ei[e]; d = ei[N_EDGES + e]; }
    else { s = e - N_EDGES; d = s; }
    int pos = atomicAdd(&cursor[d], 1);
    srcs[pos] = s;
  }
}

// ---------------- fused GEMM + es/ed + bf16-h epilogue ----------------
// C-tile per wave = 16 rows x 256 cols (all heads). Epilogue computes
// es/ed in-register (dot with a_src/a_dst + 16-lane reduce) and stores h as bf16.
// AF32: A is f32 (layer 1 reads x directly, converting during staging).
#define BM 64
#define BK 32
#define LDA 40   /* row stride in bf16 elems: 32 + 8 pad */

template<bool AF32>
__global__ __launch_bounds__(256) void gemm_fused_kernel(const void* __restrict__ Araw,
                                                         const unsigned short* __restrict__ Bt,
                                                         const float* __restrict__ a_s,
                                                         const float* __restrict__ a_d,
                                                         float* __restrict__ es,
                                                         float* __restrict__ ed,
                                                         unsigned short* __restrict__ hb,
                                                         int M, int K){
  __shared__ unsigned short Als[BM * LDA];
  __shared__ unsigned short Bls[256 * LDA];
  int tid = threadIdx.x;
  int lane = tid & 63, wid = tid >> 6;
  int l15 = lane & 15, quad = lane >> 4;
  int m0 = blockIdx.x * BM;

  f32x4 acc[16];
  #pragma unroll
  for (int t = 0; t < 16; ++t) acc[t] = (f32x4){0.f, 0.f, 0.f, 0.f};

  for (int k0 = 0; k0 < K; k0 += BK){
    __syncthreads();
    {
      int row = tid >> 2, g = tid & 3;
      int grow = m0 + row; if (grow >= M) grow = M - 1;
      if (AF32){
        const float* Af = (const float*)Araw + (size_t)grow * K + k0 + 8 * g;
        float4 v0 = *(const float4*)(Af);
        float4 v1 = *(const float4*)(Af + 4);
        ushort4 p0 = {f2bf(v0.x), f2bf(v0.y), f2bf(v0.z), f2bf(v0.w)};
        ushort4 p1 = {f2bf(v1.x), f2bf(v1.y), f2bf(v1.z), f2bf(v1.w)};
        *(ushort4*)(&Als[row * LDA + 8 * g])     = p0;
        *(ushort4*)(&Als[row * LDA + 8 * g + 4]) = p1;
      } else {
        const unsigned short* Ab = (const unsigned short*)Araw;
        uint4 av = *(const uint4*)(Ab + (size_t)grow * K + k0 + 8 * g);
        *(uint4*)(&Als[row * LDA + 8 * g]) = av;
      }
      const unsigned short* src = Bt + (size_t)tid * K + k0;
      uint4 b0 = *(const uint4*)(src);
      uint4 b1 = *(const uint4*)(src + 8);
      uint4 b2 = *(const uint4*)(src + 16);
      uint4 b3 = *(const uint4*)(src + 24);
      unsigned short* dst = &Bls[tid * LDA];
      *(uint4*)(dst) = b0;
      *(uint4*)(dst + 8) = b1;
      *(uint4*)(dst + 16) = b2;
      *(uint4*)(dst + 24) = b3;
    }
    __syncthreads();
    short8 af = *(const short8*)(&Als[(16 * wid + l15) * LDA + quad * 8]);
    #pragma unroll
    for (int t = 0; t < 16; ++t){
      short8 bf = *(const short8*)(&Bls[(16 * t + l15) * LDA + quad * 8]);
      acc[t] = __builtin_amdgcn_mfma_f32_16x16x32_bf16(af, bf, acc[t], 0, 0, 0);
    }
  }

  int row0 = m0 + 16 * wid + quad * 4;

  // store h as bf16
  #pragma unroll
  for (int t = 0; t < 16; ++t){
    int col = 16 * t + l15;
    #pragma unroll
    for (int r = 0; r < 4; ++r){
      int grow = row0 + r;
      if (grow < M) hb[(size_t)grow * WIDTH + col] = f2bf(acc[t][r]);
    }
  }

  // es/ed: per-head dot with a_src/a_dst, reduce across the 16 l15-lanes
  float as_v[16], ad_v[16];
  #pragma unroll
  for (int t = 0; t < 16; ++t){
    int cc = 16 * (t & 3) + l15;
    as_v[t] = a_s[(t >> 2) * 64 + cc];
    ad_v[t] = a_d[(t >> 2) * 64 + cc];
  }
  #pragma unroll
  for (int h = 0; h < 4; ++h){
    #pragma unroll
    for (int r = 0; r < 4; ++r){
      float se = 0.f, sd = 0.f;
      #pragma unroll
      for (int tt = 0; tt < 4; ++tt){
        int t = 4 * h + tt;
        se += acc[t][r] * as_v[t];
        sd += acc[t][r] * ad_v[t];
      }
      #pragma unroll
      for (int off = 1; off < 16; off <<= 1){
        se += __shfl_xor(se, off, 64);
        sd += __shfl_xor(sd, off, 64);
      }
      int grow = row0 + r;
      if (l15 == 0 && grow < M){
        es[grow * 4 + h] = se;
        ed[grow * 4 + h] = sd;
      }
    }
  }
}

// ---------------- aggregation: one node per HALF-wave ----------------
// 32 lanes x 8 ch (16B uint4) cover 256 ch. Pass 1 caches srcs + leaky(e) in LDS.
// Pass 2: 8-deep unrolled gathers, no cross-lane reductions (den uniform per head).
__global__ __launch_bounds__(256) void agg_kernel(const int* __restrict__ offsets,
                                                  const int* __restrict__ srcs,
                                                  const float* __restrict__ es,
                                                  const float* __restrict__ ed,
                                                  const unsigned short* __restrict__ hb,
                                                  const float* __restrict__ bias,
                                                  unsigned short* __restrict__ hout){
  __shared__ float eLds[8][64][4];
  __shared__ int   sLds[8][64];
  int wid = threadIdx.x >> 6;
  int lane = threadIdx.x & 63;
  int half = lane >> 5, l32 = lane & 31;
  int slot = wid * 2 + half;
  int n = blockIdx.x * 8 + slot;
  int base = offsets[n];
  int deg = offsets[n + 1] - base;
  float4 edv = *(const float4*)(ed + n * 4);

  // pass 1: strided over 32 lanes; cache first 64 edges in LDS; per-head max
  float m0 = -1e30f, m1 = -1e30f, m2 = -1e30f, m3 = -1e30f;
  for (int i = l32; i < deg; i += 32){
    int s = srcs[base + i];
    float4 ev = *(const float4*)(es + s * 4);
    float e0 = ev.x + edv.x, e1 = ev.y + edv.y, e2 = ev.z + edv.z, e3 = ev.w + edv.w;
    e0 = e0 > 0.f ? e0 : 0.2f * e0;
    e1 = e1 > 0.f ? e1 : 0.2f * e1;
    e2 = e2 > 0.f ? e2 : 0.2f * e2;
    e3 = e3 > 0.f ? e3 : 0.2f * e3;
    if (i < 64){
      sLds[slot][i] = s;
      *(float4*)(&eLds[slot][i][0]) = (float4){e0, e1, e2, e3};
    }
    m0 = fmaxf(m0, e0); m1 = fmaxf(m1, e1); m2 = fmaxf(m2, e2); m3 = fmaxf(m3, e3);
  }
  #pragma unroll
  for (int off = 1; off < 32; off <<= 1){
    m0 = fmaxf(m0, __shfl_xor(m0, off, 64));
    m1 = fmaxf(m1, __shfl_xor(m1, off, 64));
    m2 = fmaxf(m2, __shfl_xor(m2, off, 64));
    m3 = fmaxf(m3, __shfl_xor(m3, off, 64));
  }
  int head = l32 >> 3;                       // 8 lanes per head, 8 ch/lane
  float mh  = (head == 0) ? m0 : (head == 1) ? m1 : (head == 2) ? m2 : m3;
  float edh = (head == 0) ? edv.x : (head == 1) ? edv.y : (head == 2) ? edv.z : edv.w;

  // pass 2: 8 edges per iteration, 8 gathers in flight
  float2 a0 = {0.f,0.f}, a1 = {0.f,0.f}, a2 = {0.f,0.f}, a3 = {0.f,0.f};
  float den = 0.f;
  const unsigned short* hcol = hb + 8 * l32;
  for (int i = 0; i < deg; i += 8){
    int sidx[8]; float w[8];
    #pragma unroll
    for (int u = 0; u < 8; ++u){
      int idx = i + u;
      bool v = idx < deg;
      float le; int s;
      if (idx < 64 || !v){
        int ic = v ? idx : 0;
        if (ic >= 64) ic = 0;
        s  = sLds[slot][ic];
        le = eLds[slot][ic][head];
      } else {
        s = srcs[base + idx];
        float e = es[s * 4 + head] + edh;
        le = e > 0.f ? e : 0.2f * e;
      }
      sidx[u] = s;
      w[u] = v ? __expf(le - mh) : 0.f;
    }
    uint4 hv[8];
    #pragma unroll
    for (int u = 0; u < 8; ++u)
      hv[u] = *(const uint4*)(hcol + (size_t)sidx[u] * WIDTH);
    #pragma unroll
    for (int u = 0; u < 8; ++u){
      float wu = w[u];
      den += wu;
      a0.x += wu * __uint_as_float(hv[u].x << 16);
      a0.y += wu * __uint_as_float(hv[u].x & 0xffff0000u);
      a1.x += wu * __uint_as_float(hv[u].y << 16);
      a1.y += wu * __uint_as_float(hv[u].y & 0xffff0000u);
      a2.x += wu * __uint_as_float(hv[u].z << 16);
      a2.y += wu * __uint_as_float(hv[u].z & 0xffff0000u);
      a3.x += wu * __uint_as_float(hv[u].w << 16);
      a3.y += wu * __uint_as_float(hv[u].w & 0xffff0000u);
    }
  }
  float inv = 1.0f / den;
  const float* bp = bias + 8 * l32;
  float4 bv0 = *(const float4*)(bp);
  float4 bv1 = *(const float4*)(bp + 4);
  float o0 = fmaxf(a0.x * inv + bv0.x, 0.f);
  float o1 = fmaxf(a0.y * inv + bv0.y, 0.f);
  float o2 = fmaxf(a1.x * inv + bv0.z, 0.f);
  float o3 = fmaxf(a1.y * inv + bv0.w, 0.f);
  float o4 = fmaxf(a2.x * inv + bv1.x, 0.f);
  float o5 = fmaxf(a2.y * inv + bv1.y, 0.f);
  float o6 = fmaxf(a3.x * inv + bv1.z, 0.f);
  float o7 = fmaxf(a3.y * inv + bv1.w, 0.f);
  uint4 o;
  o.x = (unsigned)f2bf(o0) | ((unsigned)f2bf(o1) << 16);
  o.y = (unsigned)f2bf(o2) | ((unsigned)f2bf(o3) << 16);
  o.z = (unsigned)f2bf(o4) | ((unsigned)f2bf(o5) << 16);
  o.w = (unsigned)f2bf(o6) | ((unsigned)f2bf(o7) << 16);
  *(uint4*)(hout + (size_t)n * WIDTH + 8 * l32) = o;
}

// ---------------- output head as MFMA GEMM ----------------
__global__ __launch_bounds__(256) void out_gemm_kernel(const unsigned short* __restrict__ h1,
                                                       const unsigned short* __restrict__ h2,
                                                       const unsigned short* __restrict__ h3,
                                                       const unsigned short* __restrict__ WoT,
                                                       const float* __restrict__ bo,
                                                       float* __restrict__ out){
  int tid = threadIdx.x, lane = tid & 63, wid = tid >> 6;
  int l15 = lane & 15, quad = lane >> 4;
  int m0 = blockIdx.x * 64 + 16 * wid;

  f32x4 acc[3];
  #pragma unroll
  for (int t = 0; t < 3; ++t) acc[t] = (f32x4){0.f, 0.f, 0.f, 0.f};

  int arow = m0 + l15; if (arow >= N_NODES) arow = N_NODES - 1;

  #pragma unroll
  for (int part = 0; part < 3; ++part){
    const unsigned short* hp = (part == 0) ? h1 : (part == 1) ? h2 : h3;
    const unsigned short* ap = hp + (size_t)arow * WIDTH;
    #pragma unroll
    for (int k0 = 0; k0 < WIDTH; k0 += 32){
      short8 af = *(const short8*)(ap + k0 + quad * 8);
      int kk = part * WIDTH + k0;
      #pragma unroll
      for (int t = 0; t < 3; ++t){
        short8 bf = *(const short8*)(WoT + (size_t)(16 * t + l15) * KCAT + kk + quad * 8);
        acc[t] = __builtin_amdgcn_mfma_f32_16x16x32_bf16(af, bf, acc[t], 0, 0, 0);
      }
    }
  }

  int r0 = m0 + quad * 4;
  #pragma unroll
  for (int t = 0; t < 3; ++t){
    int col = 16 * t + l15;
    if (col < NCLS){
      float bc = bo[col];
      #pragma unroll
      for (int r = 0; r < 4; ++r){
        int grow = r0 + r;
        if (grow < N_NODES) out[(size_t)grow * NCLS + col] = acc[t][r] + bc;
      }
    }
  }
}

// ---------------- host launch ----------------
static inline size_t align256(size_t x){ return (x + 255) & ~(size_t)255; }

extern "C" void kernel_launch(void* const* d_in, const int* in_sizes, int n_in,
                              void* d_out, int out_size, void* d_ws, size_t ws_size,
                              hipStream_t stream) {
  const float* x   = (const float*)d_in[0];
  const int*   ei  = (const int*)  d_in[1];
  const float* W1  = (const float*)d_in[2];
  const float* as1 = (const float*)d_in[3];
  const float* ad1 = (const float*)d_in[4];
  const float* b1  = (const float*)d_in[5];
  const float* W2  = (const float*)d_in[6];
  const float* as2 = (const float*)d_in[7];
  const float* ad2 = (const float*)d_in[8];
  const float* b2  = (const float*)d_in[9];
  const float* W3  = (const float*)d_in[10];
  const float* as3 = (const float*)d_in[11];
  const float* ad3 = (const float*)d_in[12];
  const float* b3  = (const float*)d_in[13];
  const float* Wo  = (const float*)d_in[14];
  const float* bo  = (const float*)d_in[15];
  float* out = (float*)d_out;

  char* p = (char*)d_ws;
  auto take = [&](size_t bytes) -> char* { char* cur = p; p += align256(bytes); return cur; };

  unsigned short* Wt1   = (unsigned short*)take((size_t)WIDTH * F_IN * 2);
  unsigned short* Wt2   = (unsigned short*)take((size_t)WIDTH * WIDTH * 2);
  unsigned short* Wt3   = (unsigned short*)take((size_t)WIDTH * WIDTH * 2);
  unsigned short* WoT   = (unsigned short*)take((size_t)NPAD * KCAT * 2);
  unsigned short* hstage= (unsigned short*)take((size_t)N_NODES * WIDTH * 2);
  float*          es    = (float*)take((size_t)N_NODES * 4 * 4);
  float*          ed    = (float*)take((size_t)N_NODES * 4 * 4);
  unsigned short* h1b   = (unsigned short*)take((size_t)N_NODES * WIDTH * 2);
  unsigned short* h2b   = (unsigned short*)take((size_t)N_NODES * WIDTH * 2);
  unsigned short* h3b   = (unsigned short*)take((size_t)N_NODES * WIDTH * 2);
  int*            counts  = (int*)take((size_t)N_NODES * 4);
  int*            offsets = (int*)take((size_t)(N_NODES + 1) * 4);
  int*            cursor  = (int*)take((size_t)N_NODES * 4);
  int*            srcs    = (int*)take((size_t)ETOT * 4);

  // prep: weight transposes
  transpose_w_kernel<<<dim3(F_IN / 256, WIDTH), 256, 0, stream>>>(W1, Wt1, F_IN, WIDTH);
  transpose_w_kernel<<<dim3(1, WIDTH), 256, 0, stream>>>(W2, Wt2, WIDTH, WIDTH);
  transpose_w_kernel<<<dim3(1, WIDTH), 256, 0, stream>>>(W3, Wt3, WIDTH, WIDTH);
  transpose_wo_kernel<<<(NPAD * KCAT + 255) / 256, 256, 0, stream>>>(Wo, WoT);

  // CSR build
  zero_kernel<<<(N_NODES + 255) / 256, 256, 0, stream>>>(counts, N_NODES);
  hist_kernel<<<(ETOT + 255) / 256, 256, 0, stream>>>(ei, counts);
  scan_kernel<<<1, 1024, 0, stream>>>(counts, offsets, cursor, N_NODES);
  scatter_kernel<<<(ETOT + 255) / 256, 256, 0, stream>>>(ei, cursor, srcs);

  const int gemm_grid = (N_NODES + BM - 1) / BM;   // 469
  const int agg_grid  = N_NODES / 8;               // 3750

  // layer 1 (A = x, f32, converted in staging)
  gemm_fused_kernel<true><<<gemm_grid, 256, 0, stream>>>(x, Wt1, as1, ad1, es, ed, hstage, N_NODES, F_IN);
  agg_kernel<<<agg_grid, 256, 0, stream>>>(offsets, srcs, es, ed, hstage, b1, h1b);
  // layer 2
  gemm_fused_kernel<false><<<gemm_grid, 256, 0, stream>>>(h1b, Wt2, as2, ad2, es, ed, hstage, N_NODES, WIDTH);
  agg_kernel<<<agg_grid, 256, 0, stream>>>(offsets, srcs, es, ed, hstage, b2, h2b);
  // layer 3
  gemm_fused_kernel<false><<<gemm_grid, 256, 0, stream>>>(h2b, Wt3, as3, ad3, es, ed, hstage, N_NODES, WIDTH);
  agg_kernel<<<agg_grid, 256, 0, stream>>>(offsets, srcs, es, ed, hstage, b3, h3b);

  // output head (MFMA GEMM)
  out_gemm_kernel<<<gemm_grid, 256, 0, stream>>>(h1b, h2b, h3b, WoT, bo, out);
}